// Round 7
// baseline (38.760 us; speedup 1.0000x reference)
//
#include <hip/hip_runtime.h>

typedef float v2f  __attribute__((ext_vector_type(2)));
typedef float v4a4 __attribute__((ext_vector_type(4), aligned(4)));

constexpr int IN_DIM = 21;
constexpr int HID = 5;
constexpr int NG = 4 * HID;              // 20 gates
constexpr int BLK = 256;
constexpr float LOG2E = 1.44269504088896340736f;

__device__ __forceinline__ v2f splat(float s) { v2f r; r.x = s; r.y = s; return r; }
__device__ __forceinline__ v2f vfma(v2f a, v2f b, v2f c) {
    return __builtin_elementwise_fma(a, b, c);
}
__device__ __forceinline__ v2f vexp2(v2f x) {
    v2f r; r.x = __builtin_amdgcn_exp2f(x.x); r.y = __builtin_amdgcn_exp2f(x.y); return r;
}
__device__ __forceinline__ v2f vrcp(v2f x) {
    v2f r; r.x = __builtin_amdgcn_rcpf(x.x); r.y = __builtin_amdgcn_rcpf(x.y); return r;
}
__device__ __forceinline__ v2f sigmoid2(v2f x) {          // 1/(1+e^-x)
    v2f t = vexp2(x * splat(-LOG2E));
    return vrcp(t + splat(1.0f));
}
__device__ __forceinline__ v2f tanh2(v2f x) {             // 1 - 2/(e^2x+1)
    v2f t = vexp2(x * splat(2.0f * LOG2E));
    v2f r = vrcp(t + splat(1.0f));
    return vfma(splat(-2.0f), r, splat(1.0f));
}
__device__ __forceinline__ float ssig(float x)  { return 1.0f / (1.0f + __expf(-x)); }
__device__ __forceinline__ float stanh(float x) { return 1.0f - 2.0f / (__expf(2.0f * x) + 1.0f); }

__global__ __launch_bounds__(BLK, 4) void lstm2_head_pk(
    const float* __restrict__ x,
    const float* __restrict__ h0,
    const float* __restrict__ c0,
    const float* __restrict__ Wih0,
    const float* __restrict__ Whh0,
    const float* __restrict__ bih0,
    const float* __restrict__ bhh0,
    const float* __restrict__ Wih1,
    const float* __restrict__ Whh1,
    const float* __restrict__ bih1,
    const float* __restrict__ bhh1,
    const float* __restrict__ Wlin,
    const float* __restrict__ blin,
    float* __restrict__ out,
    int B)
{
    const long long e0 = 2LL * ((long long)blockIdx.x * BLK + threadIdx.x);
    if (e0 >= B) return;

    if (e0 + 1 < B) {
        // ================= fast path: element pair =================
        // ---- x pair: 42 contiguous floats; dword-aligned wide loads ----
        const float* gx = x + e0 * IN_DIM;
        float xr[2 * IN_DIM];
#pragma unroll
        for (int r = 0; r < 10; ++r)
            *(v4a4*)(xr + 4 * r) = *(const v4a4*)(gx + 4 * r);
        *(v2f*)(xr + 40) = *(const v2f*)(gx + 40);

        // ---- layer-0 gate accumulators (j-major: only 20 v2f live) ----
        v2f g[NG];
#pragma unroll
        for (int r = 0; r < NG; ++r) g[r] = splat(bih0[r] + bhh0[r]);
#pragma unroll
        for (int j = 0; j < IN_DIM; ++j) {
            v2f xp; xp.x = xr[j]; xp.y = xr[IN_DIM + j];
#pragma unroll
            for (int r = 0; r < NG; ++r)
                g[r] = vfma(splat(Wih0[r * IN_DIM + j]), xp, g[r]);
        }

        // ---- h0/c0 layer-0 state: 10 contiguous floats each ----
        const long long off1 = (long long)B * HID;
        const float* ph0 = h0 + e0 * HID;
        const float* pc0 = c0 + e0 * HID;
        float wh0[10], wc0[10];
        *(v4a4*)(wh0) = *(const v4a4*)(ph0);
        *(v4a4*)(wh0 + 4) = *(const v4a4*)(ph0 + 4);
        *(v2f*)(wh0 + 8) = *(const v2f*)(ph0 + 8);
        *(v4a4*)(wc0) = *(const v4a4*)(pc0);
        *(v4a4*)(wc0 + 4) = *(const v4a4*)(pc0 + 4);
        *(v2f*)(wc0 + 8) = *(const v2f*)(pc0 + 8);

#pragma unroll
        for (int kk = 0; kk < HID; ++kk) {
            v2f hp; hp.x = wh0[kk]; hp.y = wh0[HID + kk];
#pragma unroll
            for (int r = 0; r < NG; ++r)
                g[r] = vfma(splat(Whh0[r * HID + kk]), hp, g[r]);
        }

        // ---- layer-0 activations ----
        v2f h1[HID];
#pragma unroll
        for (int k = 0; k < HID; ++k) {
            v2f cp; cp.x = wc0[k]; cp.y = wc0[HID + k];
            v2f ig = sigmoid2(g[k]);
            v2f fg = sigmoid2(g[HID + k]);
            v2f gg = tanh2(g[2 * HID + k]);
            v2f og = sigmoid2(g[3 * HID + k]);
            v2f cn = vfma(fg, cp, ig * gg);
            h1[k] = og * tanh2(cn);
        }

        // ---- layer-1 state loads ----
        const float* ph1 = h0 + off1 + e0 * HID;
        const float* pc1 = c0 + off1 + e0 * HID;
        float wh1[10], wc1[10];
        *(v4a4*)(wh1) = *(const v4a4*)(ph1);
        *(v4a4*)(wh1 + 4) = *(const v4a4*)(ph1 + 4);
        *(v2f*)(wh1 + 8) = *(const v2f*)(ph1 + 8);
        *(v4a4*)(wc1) = *(const v4a4*)(pc1);
        *(v4a4*)(wc1 + 4) = *(const v4a4*)(pc1 + 4);
        *(v2f*)(wc1 + 8) = *(const v2f*)(pc1 + 8);

        // ---- layer-1 gates ----
#pragma unroll
        for (int r = 0; r < NG; ++r) g[r] = splat(bih1[r] + bhh1[r]);
#pragma unroll
        for (int j = 0; j < HID; ++j) {
#pragma unroll
            for (int r = 0; r < NG; ++r)
                g[r] = vfma(splat(Wih1[r * HID + j]), h1[j], g[r]);
        }
#pragma unroll
        for (int kk = 0; kk < HID; ++kk) {
            v2f hp; hp.x = wh1[kk]; hp.y = wh1[HID + kk];
#pragma unroll
            for (int r = 0; r < NG; ++r)
                g[r] = vfma(splat(Whh1[r * HID + kk]), hp, g[r]);
        }

        // ---- layer-1 activations + head ----
        v2f o = splat(blin[0]);
#pragma unroll
        for (int k = 0; k < HID; ++k) {
            v2f cp; cp.x = wc1[k]; cp.y = wc1[HID + k];
            v2f ig = sigmoid2(g[k]);
            v2f fg = sigmoid2(g[HID + k]);
            v2f gg = tanh2(g[2 * HID + k]);
            v2f og = sigmoid2(g[3 * HID + k]);
            v2f cn = vfma(fg, cp, ig * gg);
            v2f h2 = og * tanh2(cn);
            o = vfma(splat(Wlin[k]), h2, o);
        }
        v2f r = tanh2(o);
        *(v2f*)(out + e0) = r;                            // 8B store, e0 even
    } else {
        // ================= scalar tail (single element) =================
        const long long e = e0;
        float xi[IN_DIM];
        for (int j = 0; j < IN_DIM; ++j) xi[j] = x[e * IN_DIM + j];
        float hp[HID], cp[HID], gg[NG], hh1[HID], hh2[HID];
        for (int k = 0; k < HID; ++k) { hp[k] = h0[e * HID + k]; cp[k] = c0[e * HID + k]; }
        for (int rr = 0; rr < NG; ++rr) {
            float acc = bih0[rr] + bhh0[rr];
            for (int j = 0; j < IN_DIM; ++j) acc = fmaf(Wih0[rr * IN_DIM + j], xi[j], acc);
            for (int k = 0; k < HID; ++k)    acc = fmaf(Whh0[rr * HID + k], hp[k], acc);
            gg[rr] = acc;
        }
        for (int k = 0; k < HID; ++k) {
            float cn = fmaf(ssig(gg[HID + k]), cp[k], ssig(gg[k]) * stanh(gg[2 * HID + k]));
            hh1[k] = ssig(gg[3 * HID + k]) * stanh(cn);
        }
        const long long off1 = (long long)B * HID;
        for (int k = 0; k < HID; ++k) { hp[k] = h0[off1 + e * HID + k]; cp[k] = c0[off1 + e * HID + k]; }
        for (int rr = 0; rr < NG; ++rr) {
            float acc = bih1[rr] + bhh1[rr];
            for (int j = 0; j < HID; ++j) acc = fmaf(Wih1[rr * HID + j], hh1[j], acc);
            for (int k = 0; k < HID; ++k) acc = fmaf(Whh1[rr * HID + k], hp[k], acc);
            gg[rr] = acc;
        }
        for (int k = 0; k < HID; ++k) {
            float cn = fmaf(ssig(gg[HID + k]), cp[k], ssig(gg[k]) * stanh(gg[2 * HID + k]));
            hh2[k] = ssig(gg[3 * HID + k]) * stanh(cn);
        }
        float o = blin[0];
        for (int k = 0; k < HID; ++k) o = fmaf(Wlin[k], hh2[k], o);
        out[e] = stanh(o);
    }
}

extern "C" void kernel_launch(void* const* d_in, const int* in_sizes, int n_in,
                              void* d_out, int out_size, void* d_ws, size_t ws_size,
                              hipStream_t stream) {
    const float* x    = (const float*)d_in[0];
    const float* h0   = (const float*)d_in[1];
    const float* c0   = (const float*)d_in[2];
    const float* Wih0 = (const float*)d_in[3];
    const float* Whh0 = (const float*)d_in[4];
    const float* bih0 = (const float*)d_in[5];
    const float* bhh0 = (const float*)d_in[6];
    const float* Wih1 = (const float*)d_in[7];
    const float* Whh1 = (const float*)d_in[8];
    const float* bih1 = (const float*)d_in[9];
    const float* bhh1 = (const float*)d_in[10];
    const float* Wlin = (const float*)d_in[11];
    const float* blin = (const float*)d_in[12];
    float* out = (float*)d_out;

    const int B = in_sizes[0] / IN_DIM;
    const int epb = 2 * BLK;
    const int grid = (B + epb - 1) / epb;
    lstm2_head_pk<<<grid, BLK, 0, stream>>>(
        x, h0, c0, Wih0, Whh0, bih0, bhh0, Wih1, Whh1, bih1, bhh1,
        Wlin, blin, out, B);
}